// Round 11
// baseline (270.115 us; speedup 1.0000x reference)
//
#include <hip/hip_runtime.h>
#include <stdint.h>

typedef int  v4i  __attribute__((ext_vector_type(4)));
typedef int  v16i __attribute__((ext_vector_type(16)));
typedef unsigned int uint32;

#define BATCH 16384
#define FEAT  1024

// ---- workspace layout (bytes) ----
// Activations/weights in MFMA fragment layout: frag16B idx = (tile*32+kk)*64+lane
//   byte j of lane = val[row = kk*32 + (j&3)+8*(j>>2)+4*(lane>>5)][col = tile*32 + (lane&31)]
// W rows with BN scale < 0 sign-folded at prep. Thresholds stored in SIGMA
// order: TH[l*1024 + mt*32 + hi*16 + q] = t2(row = mt*32+(q&3)+8*(q>>2)+4*hi).
#define OFF_ACTA 0u            // 16 MB  (packed X)
#define OFF_ACTB 16777216u     // (unused — kept for layout stability)
#define OFF_WA1  33554432u     // 1 MB
#define OFF_WA2  34603008u     // 1 MB
#define OFF_WA3  35651584u     // 1 MB
#define OFF_WA4  36700160u     // 32 KB (10 rows + 22 zero-pad rows)
#define OFF_TH   36732928u     // 3*1024 int (sigma order)

// ---------------------------------------------------------------------------
// prep (R4-verified; TH in sigma order as of R8).
__global__ void __launch_bounds__(256) prep_kernel(
    const float* __restrict__ x,
    const float* __restrict__ W1, const float* __restrict__ W2,
    const float* __restrict__ W3, const float* __restrict__ W4,
    const float* __restrict__ g1, const float* __restrict__ b1,
    const float* __restrict__ m1, const float* __restrict__ v1,
    const float* __restrict__ g2, const float* __restrict__ b2,
    const float* __restrict__ m2, const float* __restrict__ v2,
    const float* __restrict__ g3, const float* __restrict__ b3,
    const float* __restrict__ m3, const float* __restrict__ v3,
    char* __restrict__ actA, char* __restrict__ wa1, char* __restrict__ wa2,
    char* __restrict__ wa3, char* __restrict__ wa4, int* __restrict__ TH)
{
    int b = blockIdx.x;
    if (b == 609) {                       // thresholds, sign-folded, sigma order
        for (int gid = threadIdx.x; gid < 3072; gid += 256) {
            int l = gid >> 10, j = gid & 1023;
            const float *g, *bb, *m, *v;
            if (l == 0)      { g = g1; bb = b1; m = m1; v = v1; }
            else if (l == 1) { g = g2; bb = b2; m = m2; v = v2; }
            else             { g = g3; bb = b3; m = m3; v = v3; }
            double gd = (double)g[j], bd = (double)bb[j], md = (double)m[j], vd = (double)v[j];
            double s = gd / sqrt(vd + 1e-5);
            int t2;
            if (s > 0.0)      t2 = (int)ceil(md - bd / s);           // bit = h >= t2
            else if (s < 0.0) t2 = -(int)floor(md - bd / s);         // folded
            else              t2 = (bd >= 0.0) ? -2000000 : 2000000; // always / never
            int sidx = (j >> 5) * 32 + ((j >> 2) & 1) * 16 + (j & 3) + 4 * ((j & 31) >> 3);
            TH[l * 1024 + sidx] = t2;
        }
        return;
    }

    const float* src; char* dst; float thr; int nrows; int dblk;
    const float* gp = nullptr;
    if (b < 512)      { src = x  + (size_t)b * 32768;            dst = actA; dblk = b;      thr = 0.5f; nrows = 32; }
    else if (b < 544) { int mb = b - 512; src = W1 + (size_t)mb * 32768; dst = wa1; dblk = mb; thr = 0.0f; nrows = 32; gp = g1; }
    else if (b < 576) { int mb = b - 544; src = W2 + (size_t)mb * 32768; dst = wa2; dblk = mb; thr = 0.0f; nrows = 32; gp = g2; }
    else if (b < 608) { int mb = b - 576; src = W3 + (size_t)mb * 32768; dst = wa3; dblk = mb; thr = 0.0f; nrows = 32; gp = g3; }
    else              { src = W4; dst = wa4; dblk = 0; thr = 0.0f; nrows = 10; }

    __shared__ unsigned char T[32][1040];
#pragma unroll
    for (int u = 0; u < 8; ++u) {
        int unit = threadIdx.x + u * 256;      // 0..2047
        int row  = unit >> 6;                  // 0..31
        int c16  = (unit & 63) << 4;           // col base (16 floats)
        uint32 wb0 = 0, wb1 = 0, wb2 = 0, wb3 = 0;
        if (row < nrows) {
            bool flipb = gp && (gp[dblk * 32 + row] < 0.0f);
            const float* p = src + (size_t)row * 1024 + c16;
            float4 f0 = *(const float4*)(p + 0);
            float4 f1 = *(const float4*)(p + 4);
            float4 f2 = *(const float4*)(p + 8);
            float4 f3 = *(const float4*)(p + 12);
#define BY(f) ((((f) >= thr) != flipb) ? 0x01u : 0xFFu)
            wb0 = BY(f0.x) | (BY(f0.y)<<8) | (BY(f0.z)<<16) | (BY(f0.w)<<24);
            wb1 = BY(f1.x) | (BY(f1.y)<<8) | (BY(f1.z)<<16) | (BY(f1.w)<<24);
            wb2 = BY(f2.x) | (BY(f2.y)<<8) | (BY(f2.z)<<16) | (BY(f2.w)<<24);
            wb3 = BY(f3.x) | (BY(f3.y)<<8) | (BY(f3.z)<<16) | (BY(f3.w)<<24);
#undef BY
        }
        *(uint4*)&T[row][c16] = make_uint4(wb0, wb1, wb2, wb3);
    }
    __syncthreads();

    int lane = threadIdx.x & 63;
    int wv   = threadIdx.x >> 6;
    int row  = lane & 31;
    int hb   = (lane >> 5) * 4;                 // +4h byte offset of sigma
#pragma unroll
    for (int u = 0; u < 8; ++u) {
        int kk = wv * 8 + u;
        const unsigned char* tr = &T[row][kk * 32 + hb];
        uint32 w0 = *(const uint32*)(tr + 0);
        uint32 w1 = *(const uint32*)(tr + 8);
        uint32 w2 = *(const uint32*)(tr + 16);
        uint32 w3 = *(const uint32*)(tr + 24);
        *(uint4*)(dst + (((size_t)dblk * 32 + kk) * 64 + lane) * 16) = make_uint4(w0, w1, w2, w3);
    }
}

// ---------------------------------------------------------------------------
__device__ __forceinline__ void gload16(const v4i* gsrc, v4i* ldst) {
    __builtin_amdgcn_global_load_lds(
        (const __attribute__((address_space(1))) void*)gsrc,
        (__attribute__((address_space(3))) void*)ldst, 16, 0, 0);
}

#define MFMA(a, b, c) __builtin_amdgcn_mfma_i32_32x32x32_i8((a), (b), (c), 0, 0, 0)

// ---------------------------------------------------------------------------
// R11: R10 kernel with the kk loop FULLY unrolled. R10's unroll-2 body hid the
// next iterations' loads behind the loop backedge (compiler cannot hoist
// across it), leaving contended-L2 latency exposed each body => the three
// pipes serialized (MFMA 7.8 + L2 7.3 + LDS 5.1 ~= 20.2 us/layer, measured
// 20.9). Full unroll makes all addresses static so the compiler software-
// pipelines with named registers up to the 128-VGPR cap (no arrays => no
// R9-style scratch spill). Skew retained (order-independent integer accum).
__global__ void __launch_bounds__(1024, 4) net_kernel(
    const v4i* __restrict__ Xp,  const v4i* __restrict__ Wp1,
    const v4i* __restrict__ Wp2, const v4i* __restrict__ Wp3,
    const v4i* __restrict__ Wp4, const int* __restrict__ TH,
    const float* __restrict__ tw, const float* __restrict__ tb,
    const float* __restrict__ tm, const float* __restrict__ tv,
    float* __restrict__ out)
{
    __shared__ v4i Hs[4096];               // 64 KB: frag f = nb*32+kk at f*64+lane
    const int tid  = threadIdx.x;
    const int lane = tid & 63;
    const int wv   = tid >> 6;             // 0..15
    const int hi   = lane >> 5;
    const int blk  = blockIdx.x;           // 0..255, owns cols blk*64..+63

    // ---- load packed X for this block's 2 nb tiles (64 KB, linear) ----
    {
        const v4i* src = Xp + (size_t)blk * 4096;
#pragma unroll
        for (int j = 0; j < 4; ++j)
            gload16(src + j * 1024 + wv * 64 + lane, &Hs[j * 1024 + wv * 64]);
    }
    asm volatile("s_waitcnt vmcnt(0)" ::: "memory");
    __syncthreads();

    const int mt0 = wv * 2, mt1 = wv * 2 + 1;
    const int kk0 = (wv * 2) & 31;         // per-wave ring start (skew)

#pragma unroll 1
    for (int l = 0; l < 3; ++l) {
        const v4i* W = (l == 0) ? Wp1 : (l == 1) ? Wp2 : Wp3;
        const int* thl = TH + l * 1024;

        // acc pre-initialized with -T2 (sigma-ordered threshold load)
        v16i acc00, acc01, acc10, acc11;
        {
            const int4* t0 = (const int4*)(thl + mt0 * 32 + hi * 16);
            const int4* t1 = (const int4*)(thl + mt1 * 32 + hi * 16);
#pragma unroll
            for (int g = 0; g < 4; ++g) {
                int4 ta = t0[g], tc = t1[g];
                acc00[4*g+0] = -ta.x; acc00[4*g+1] = -ta.y;
                acc00[4*g+2] = -ta.z; acc00[4*g+3] = -ta.w;
                acc10[4*g+0] = -tc.x; acc10[4*g+1] = -tc.y;
                acc10[4*g+2] = -tc.z; acc10[4*g+3] = -tc.w;
            }
#pragma unroll
            for (int q = 0; q < 16; ++q) { acc01[q] = acc00[q]; acc11[q] = acc10[q]; }
        }

        const v4i* A0 = W + (size_t)mt0 * 2048 + lane;
        const v4i* A1 = W + (size_t)mt1 * 2048 + lane;
#pragma unroll
        for (int ks = 0; ks < 32; ++ks) {      // FULL unroll: static addresses,
            const int k = (ks + kk0) & 31;     // global scheduling across layer
            v4i b0 = Hs[k * 64 + lane];
            v4i b1 = Hs[(32 + k) * 64 + lane];
            v4i a0 = A0[k * 64];
            v4i a1 = A1[k * 64];
            acc00 = MFMA(a0, b0, acc00);
            acc01 = MFMA(a0, b1, acc01);
            acc10 = MFMA(a1, b0, acc10);
            acc11 = MFMA(a1, b1, acc11);
        }

        // threshold -> bytes (h includes -T2; byte = sign: +1->0x01, -1->0xFF)
        uint32 w00[4], w01[4], w10[4], w11[4];
#pragma unroll
        for (int g = 0; g < 4; ++g) {
            uint32 d00 = 0, d01 = 0, d10 = 0, d11 = 0;
#pragma unroll
            for (int bq = 0; bq < 4; ++bq) {
                int q = 4 * g + bq;
                d00 |= (((uint32)((acc00[q] >> 31) | 1)) & 0xFFu) << (8 * bq);
                d01 |= (((uint32)((acc01[q] >> 31) | 1)) & 0xFFu) << (8 * bq);
                d10 |= (((uint32)((acc10[q] >> 31) | 1)) & 0xFFu) << (8 * bq);
                d11 |= (((uint32)((acc11[q] >> 31) | 1)) & 0xFFu) << (8 * bq);
            }
            w00[g] = d00; w01[g] = d01; w10[g] = d10; w11[g] = d11;
        }

        __syncthreads();                   // all waves done READING Hs
        {
            v4i o;
            o[0] = (int)w00[0]; o[1] = (int)w00[1]; o[2] = (int)w00[2]; o[3] = (int)w00[3];
            Hs[(0 * 32 + mt0) * 64 + lane] = o;      // (mt0, nb0)
            o[0] = (int)w01[0]; o[1] = (int)w01[1]; o[2] = (int)w01[2]; o[3] = (int)w01[3];
            Hs[(32 + mt0) * 64 + lane] = o;          // (mt0, nb1)
            o[0] = (int)w10[0]; o[1] = (int)w10[1]; o[2] = (int)w10[2]; o[3] = (int)w10[3];
            Hs[(0 * 32 + mt1) * 64 + lane] = o;      // (mt1, nb0)
            o[0] = (int)w11[0]; o[1] = (int)w11[1]; o[2] = (int)w11[2]; o[3] = (int)w11[3];
            Hs[(32 + mt1) * 64 + lane] = o;          // (mt1, nb1)
        }
        __syncthreads();                   // new layer visible to all waves
    }

    // ---- final 1024 -> 10 (W4 zero-padded to 32 rows) + TensorNorm ----
    if (wv < 2) {
        const int nb = wv;
        v16i acc;
#pragma unroll
        for (int z = 0; z < 16; ++z) acc[z] = 0;
#pragma unroll
        for (int kk = 0; kk < 32; ++kk) {
            v4i av = Wp4[kk * 64 + lane];
            v4i bv = Hs[(nb * 32 + kk) * 64 + lane];
            acc = MFMA(av, bv, acc);
        }
        double sc  = (double)tw[0] / sqrt((double)tv[0] + 1e-4);
        double off = (double)tb[0] - (double)tm[0] * sc;
        int colg = blk * 64 + nb * 32 + (lane & 31);
#pragma unroll
        for (int q = 0; q < 8; ++q) {
            int rr = (q & 3) + 8 * (q >> 2) + 4 * hi;
            if (rr < 10)
                out[(size_t)colg * 10 + rr] = (float)((double)acc[q] * sc + off);
        }
    }
}

// ---------------------------------------------------------------------------
extern "C" void kernel_launch(void* const* d_in, const int* in_sizes, int n_in,
                              void* d_out, int out_size, void* d_ws, size_t ws_size,
                              hipStream_t stream) {
    const float* x  = (const float*)d_in[0];
    const float* W1 = (const float*)d_in[1];
    const float* W2 = (const float*)d_in[2];
    const float* W3 = (const float*)d_in[3];
    const float* W4 = (const float*)d_in[4];
    const float* g1 = (const float*)d_in[5];
    const float* b1 = (const float*)d_in[6];
    const float* m1 = (const float*)d_in[7];
    const float* v1 = (const float*)d_in[8];
    const float* g2 = (const float*)d_in[9];
    const float* b2 = (const float*)d_in[10];
    const float* m2 = (const float*)d_in[11];
    const float* v2 = (const float*)d_in[12];
    const float* g3 = (const float*)d_in[13];
    const float* b3 = (const float*)d_in[14];
    const float* m3 = (const float*)d_in[15];
    const float* v3 = (const float*)d_in[16];
    const float* tw = (const float*)d_in[17];
    const float* tb = (const float*)d_in[18];
    const float* tm = (const float*)d_in[19];
    const float* tv = (const float*)d_in[20];

    char* ws = (char*)d_ws;
    char* actA = ws + OFF_ACTA;
    char* wa1  = ws + OFF_WA1;
    char* wa2  = ws + OFF_WA2;
    char* wa3  = ws + OFF_WA3;
    char* wa4  = ws + OFF_WA4;
    int*  TH   = (int*)(ws + OFF_TH);

    prep_kernel<<<610, 256, 0, stream>>>(x, W1, W2, W3, W4,
                                         g1, b1, m1, v1, g2, b2, m2, v2,
                                         g3, b3, m3, v3,
                                         actA, wa1, wa2, wa3, wa4, TH);

    net_kernel<<<256, 1024, 0, stream>>>((const v4i*)actA,
                                         (const v4i*)wa1, (const v4i*)wa2,
                                         (const v4i*)wa3, (const v4i*)wa4,
                                         TH, tw, tb, tm, tv, (float*)d_out);
}

// Round 12
// 172.719 us; speedup vs baseline: 1.5639x; 1.5639x over previous
//
#include <hip/hip_runtime.h>
#include <stdint.h>

typedef int   v4i  __attribute__((ext_vector_type(4)));
typedef int   v8i  __attribute__((ext_vector_type(8)));
typedef float v16f __attribute__((ext_vector_type(16)));
typedef unsigned int uint32;

#define BATCH 16384
#define FEAT  1024

// ---- workspace layout (bytes) ----
// R12: MXFP4 everywhere (values +-1 -> e2m1 0x2/0xA; pad rows 0x0). Frag =
// 64 lanes x 16B = 32 nibbles/lane covering K=64. Logical k (hi=lane>>5, i) of
// frag f maps to model index ρ = 64f + (i>>4)*32 + σ4(i&15) + 4*hi, with
// σ4(q) = (q&3)+8*(q>>2). This makes the producer's C-register nibbles land
// verbatim in its own lane's B-frag slot (no cross-lane traffic), same trick
// as the verified i8 pipeline, re-derived for K=64. W sign-folded at prep;
// thresholds (sigma order, R8-verified) init the f32 accumulator (exact ints).
#define OFF_ACTA 0u            // 8 MB  (packed X, fp4)
#define OFF_ACTB 16777216u     // (unused — kept for layout stability)
#define OFF_WA1  33554432u     // 512 KB
#define OFF_WA2  34603008u     // 512 KB
#define OFF_WA3  35651584u     // 512 KB
#define OFF_WA4  36700160u     // 16 KB (10 rows + 22 zero rows)
#define OFF_TH   36732928u     // 3*1024 int (sigma order)

// ---------------------------------------------------------------------------
// bytes {0x01,0xFF,0x00} -> fp4 nibbles {+1=0x2,-1=0xA,0=0x0}; 8 bytes -> dword
__device__ __forceinline__ uint32 nib8(uint32 lo, uint32 hb) {
    uint32 r = 0u;
#pragma unroll
    for (int j = 0; j < 4; ++j) {
        uint32 b = (lo >> (8 * j)) & 0xFFu;
        r |= (((b & 8u) | ((b & 1u) << 1)) << (4 * j));
    }
#pragma unroll
    for (int j = 0; j < 4; ++j) {
        uint32 b = (hb >> (8 * j)) & 0xFFu;
        r |= (((b & 8u) | ((b & 1u) << 1)) << (4 * j + 16));
    }
    return r;
}

// ---------------------------------------------------------------------------
// prep: binarize (sign-folded W) and emit fp4 fragments in rho order.
// Roles: b<512: X (thr 0.5) | 512..607: W1..3 | 608: W4 | 609: TH (sigma order)
__global__ void __launch_bounds__(256) prep_kernel(
    const float* __restrict__ x,
    const float* __restrict__ W1, const float* __restrict__ W2,
    const float* __restrict__ W3, const float* __restrict__ W4,
    const float* __restrict__ g1, const float* __restrict__ b1,
    const float* __restrict__ m1, const float* __restrict__ v1,
    const float* __restrict__ g2, const float* __restrict__ b2,
    const float* __restrict__ m2, const float* __restrict__ v2,
    const float* __restrict__ g3, const float* __restrict__ b3,
    const float* __restrict__ m3, const float* __restrict__ v3,
    char* __restrict__ actA, char* __restrict__ wa1, char* __restrict__ wa2,
    char* __restrict__ wa3, char* __restrict__ wa4, int* __restrict__ TH)
{
    int b = blockIdx.x;
    if (b == 609) {                       // thresholds, sign-folded, sigma order
        for (int gid = threadIdx.x; gid < 3072; gid += 256) {
            int l = gid >> 10, j = gid & 1023;
            const float *g, *bb, *m, *v;
            if (l == 0)      { g = g1; bb = b1; m = m1; v = v1; }
            else if (l == 1) { g = g2; bb = b2; m = m2; v = v2; }
            else             { g = g3; bb = b3; m = m3; v = v3; }
            double gd = (double)g[j], bd = (double)bb[j], md = (double)m[j], vd = (double)v[j];
            double s = gd / sqrt(vd + 1e-5);
            int t2;
            if (s > 0.0)      t2 = (int)ceil(md - bd / s);           // bit = h >= t2
            else if (s < 0.0) t2 = -(int)floor(md - bd / s);         // folded
            else              t2 = (bd >= 0.0) ? -2000000 : 2000000; // always / never
            int sidx = (j >> 5) * 32 + ((j >> 2) & 1) * 16 + (j & 3) + 4 * ((j & 31) >> 3);
            TH[l * 1024 + sidx] = t2;
        }
        return;
    }

    const float* src; char* dst; float thr; int nrows; int dblk;
    const float* gp = nullptr;
    if (b < 512)      { src = x  + (size_t)b * 32768;            dst = actA; dblk = b;      thr = 0.5f; nrows = 32; }
    else if (b < 544) { int mb = b - 512; src = W1 + (size_t)mb * 32768; dst = wa1; dblk = mb; thr = 0.0f; nrows = 32; gp = g1; }
    else if (b < 576) { int mb = b - 544; src = W2 + (size_t)mb * 32768; dst = wa2; dblk = mb; thr = 0.0f; nrows = 32; gp = g2; }
    else if (b < 608) { int mb = b - 576; src = W3 + (size_t)mb * 32768; dst = wa3; dblk = mb; thr = 0.0f; nrows = 32; gp = g3; }
    else              { src = W4; dst = wa4; dblk = 0; thr = 0.0f; nrows = 10; }

    __shared__ unsigned char T[32][1040];
#pragma unroll
    for (int u = 0; u < 8; ++u) {
        int unit = threadIdx.x + u * 256;      // 0..2047
        int row  = unit >> 6;                  // 0..31
        int c16  = (unit & 63) << 4;           // col base (16 floats)
        uint32 wb0 = 0, wb1 = 0, wb2 = 0, wb3 = 0;   // 0x00 for pad rows -> fp4 zero
        if (row < nrows) {
            bool flipb = gp && (gp[dblk * 32 + row] < 0.0f);
            const float* p = src + (size_t)row * 1024 + c16;
            float4 f0 = *(const float4*)(p + 0);
            float4 f1 = *(const float4*)(p + 4);
            float4 f2 = *(const float4*)(p + 8);
            float4 f3 = *(const float4*)(p + 12);
#define BY(f) ((((f) >= thr) != flipb) ? 0x01u : 0xFFu)
            wb0 = BY(f0.x) | (BY(f0.y)<<8) | (BY(f0.z)<<16) | (BY(f0.w)<<24);
            wb1 = BY(f1.x) | (BY(f1.y)<<8) | (BY(f1.z)<<16) | (BY(f1.w)<<24);
            wb2 = BY(f2.x) | (BY(f2.y)<<8) | (BY(f2.z)<<16) | (BY(f2.w)<<24);
            wb3 = BY(f3.x) | (BY(f3.y)<<8) | (BY(f3.z)<<16) | (BY(f3.w)<<24);
#undef BY
        }
        *(uint4*)&T[row][c16] = make_uint4(wb0, wb1, wb2, wb3);
    }
    __syncthreads();

    // gather fp4 frags in rho order: frag f, lane (c=lane&31, hi), dword d:
    //   base = 64f + (d>>1)*32 + (d&1)*16 + 4hi; bytes base+{0..3} and base+{8..11}
    int lane = threadIdx.x & 63;
    int wq   = threadIdx.x >> 6;               // 0..3
    int c    = lane & 31;
    int hi   = lane >> 5;
#pragma unroll
    for (int u = 0; u < 4; ++u) {
        int f = wq * 4 + u;
        uint32 dw0, dw1, dw2, dw3;
        {
            int base = 64 * f + 4 * hi;
            dw0 = nib8(*(const uint32*)&T[c][base],      *(const uint32*)&T[c][base + 8]);
            dw1 = nib8(*(const uint32*)&T[c][base + 16], *(const uint32*)&T[c][base + 24]);
            dw2 = nib8(*(const uint32*)&T[c][base + 32], *(const uint32*)&T[c][base + 40]);
            dw3 = nib8(*(const uint32*)&T[c][base + 48], *(const uint32*)&T[c][base + 56]);
        }
        *(uint4*)(dst + (((size_t)dblk * 16 + f) * 64 + lane) * 16) = make_uint4(dw0, dw1, dw2, dw3);
    }
}

// ---------------------------------------------------------------------------
__device__ __forceinline__ void gload16(const v4i* gsrc, v4i* ldst) {
    __builtin_amdgcn_global_load_lds(
        (const __attribute__((address_space(1))) void*)gsrc,
        (__attribute__((address_space(3))) void*)ldst, 16, 0, 0);
}

// fp4 MX MFMA, scale = 1.0 (E8M0 0x7F); formats: cbsz=4 (fp4), blgp=4 (fp4)
__device__ __forceinline__ v16f MFMA4(v4i a, v4i b, v16f c) {
    v8i av; av[0] = a[0]; av[1] = a[1]; av[2] = a[2]; av[3] = a[3];
    av[4] = 0; av[5] = 0; av[6] = 0; av[7] = 0;
    v8i bv; bv[0] = b[0]; bv[1] = b[1]; bv[2] = b[2]; bv[3] = b[3];
    bv[4] = 0; bv[5] = 0; bv[6] = 0; bv[7] = 0;
    return __builtin_amdgcn_mfma_scale_f32_32x32x64_f8f6f4(
        av, bv, c, 4, 4, 0, 0x7F7F7F7F, 0, 0x7F7F7F7F);
}

// ---------------------------------------------------------------------------
// R12 net: R10's verified structure (unroll-2 loop, f-ring skew, no prefetch
// arrays) ported to fp4 K=64. Per layer: 16 f-frags, 4 MFMAs each. H in LDS =
// 32 KB. Accumulate f32 (exact: all partial sums are integers < 2^24), init
// with -T2. Epilogue packs 16 nibbles -> one 16B slot per (nb,wv): verbatim
// producer->consumer layout.
__global__ void __launch_bounds__(1024, 4) net_kernel(
    const v4i* __restrict__ Xp,  const v4i* __restrict__ Wp1,
    const v4i* __restrict__ Wp2, const v4i* __restrict__ Wp3,
    const v4i* __restrict__ Wp4, const int* __restrict__ TH,
    const float* __restrict__ tw, const float* __restrict__ tb,
    const float* __restrict__ tm, const float* __restrict__ tv,
    float* __restrict__ out)
{
    __shared__ v4i Hs[2048];               // 32 KB: frag g = nb*16+f at g*64+lane
    const int tid  = threadIdx.x;
    const int lane = tid & 63;
    const int wv   = tid >> 6;             // 0..15
    const int hi   = lane >> 5;
    const int blk  = blockIdx.x;           // 0..255, owns cols blk*64..+63

    // ---- load packed X for this block's 2 nb tiles (32 KB, linear) ----
    {
        const v4i* src = Xp + (size_t)blk * 2048;
#pragma unroll
        for (int j = 0; j < 2; ++j)
            gload16(src + j * 1024 + wv * 64 + lane, &Hs[j * 1024 + wv * 64]);
    }
    asm volatile("s_waitcnt vmcnt(0)" ::: "memory");
    __syncthreads();

    const int mt0 = wv * 2, mt1 = wv * 2 + 1;
    const int f0s = wv & 15;               // per-wave f-ring start (skew)

#pragma unroll 1
    for (int l = 0; l < 3; ++l) {
        const v4i* W = (l == 0) ? Wp1 : (l == 1) ? Wp2 : Wp3;
        const int* thl = TH + l * 1024;

        // f32 acc pre-initialized with -T2 (exact integers)
        v16f acc00, acc01, acc10, acc11;
        {
            const int4* t0 = (const int4*)(thl + mt0 * 32 + hi * 16);
            const int4* t1 = (const int4*)(thl + mt1 * 32 + hi * 16);
#pragma unroll
            for (int g = 0; g < 4; ++g) {
                int4 ta = t0[g], tc = t1[g];
                acc00[4*g+0] = -(float)ta.x; acc00[4*g+1] = -(float)ta.y;
                acc00[4*g+2] = -(float)ta.z; acc00[4*g+3] = -(float)ta.w;
                acc10[4*g+0] = -(float)tc.x; acc10[4*g+1] = -(float)tc.y;
                acc10[4*g+2] = -(float)tc.z; acc10[4*g+3] = -(float)tc.w;
            }
#pragma unroll
            for (int q = 0; q < 16; ++q) { acc01[q] = acc00[q]; acc11[q] = acc10[q]; }
        }

        const v4i* A0 = W + (size_t)mt0 * 16 * 64 + lane;
        const v4i* A1 = W + (size_t)mt1 * 16 * 64 + lane;
#pragma unroll 2
        for (int fs = 0; fs < 16; ++fs) {
            const int f = (fs + f0s) & 15;     // skewed ring (named scalar)
            v4i b0 = Hs[f * 64 + lane];
            v4i b1 = Hs[(16 + f) * 64 + lane];
            v4i a0 = A0[f * 64];
            v4i a1 = A1[f * 64];
            acc00 = MFMA4(a0, b0, acc00);
            acc01 = MFMA4(a0, b1, acc01);
            acc10 = MFMA4(a1, b0, acc10);
            acc11 = MFMA4(a1, b1, acc11);
        }

        // pack: bit q = (h >= 0); nibble = 0x2 (+1) else 0xA (-1)
#define NB4(h) (((h) >= 0.0f) ? 2u : 10u)
        uint32 p00a = 0, p00b = 0, p01a = 0, p01b = 0;
        uint32 p10a = 0, p10b = 0, p11a = 0, p11b = 0;
#pragma unroll
        for (int j = 0; j < 8; ++j) {
            p00a |= NB4(acc00[j]) << (4 * j);  p00b |= NB4(acc00[8 + j]) << (4 * j);
            p01a |= NB4(acc01[j]) << (4 * j);  p01b |= NB4(acc01[8 + j]) << (4 * j);
            p10a |= NB4(acc10[j]) << (4 * j);  p10b |= NB4(acc10[8 + j]) << (4 * j);
            p11a |= NB4(acc11[j]) << (4 * j);  p11b |= NB4(acc11[8 + j]) << (4 * j);
        }
#undef NB4

        __syncthreads();                   // all waves done READING Hs
        {
            // frag f=wv: nibbles 0..15 = tile mt0 (=2wv), 16..31 = tile mt1
            v4i o;
            o[0] = (int)p00a; o[1] = (int)p00b; o[2] = (int)p10a; o[3] = (int)p10b;
            Hs[(0 * 16 + wv) * 64 + lane] = o;       // nb0
            o[0] = (int)p01a; o[1] = (int)p01b; o[2] = (int)p11a; o[3] = (int)p11b;
            Hs[(16 + wv) * 64 + lane] = o;           // nb1
        }
        __syncthreads();                   // new layer visible to all waves
    }

    // ---- final 1024 -> 10 (W4 zero-padded rows = fp4 0.0) + TensorNorm ----
    if (wv < 2) {
        const int nb = wv;
        v16f acc;
#pragma unroll
        for (int z = 0; z < 16; ++z) acc[z] = 0.0f;
#pragma unroll
        for (int f = 0; f < 16; ++f) {
            v4i av = Wp4[f * 64 + lane];
            v4i bv = Hs[(nb * 16 + f) * 64 + lane];
            acc = MFMA4(av, bv, acc);
        }
        double sc  = (double)tw[0] / sqrt((double)tv[0] + 1e-4);
        double off = (double)tb[0] - (double)tm[0] * sc;
        int colg = blk * 64 + nb * 32 + (lane & 31);
#pragma unroll
        for (int q = 0; q < 8; ++q) {
            int rr = (q & 3) + 8 * (q >> 2) + 4 * hi;
            if (rr < 10)
                out[(size_t)colg * 10 + rr] = (float)((double)acc[q] * sc + off);
        }
    }
}

// ---------------------------------------------------------------------------
extern "C" void kernel_launch(void* const* d_in, const int* in_sizes, int n_in,
                              void* d_out, int out_size, void* d_ws, size_t ws_size,
                              hipStream_t stream) {
    const float* x  = (const float*)d_in[0];
    const float* W1 = (const float*)d_in[1];
    const float* W2 = (const float*)d_in[2];
    const float* W3 = (const float*)d_in[3];
    const float* W4 = (const float*)d_in[4];
    const float* g1 = (const float*)d_in[5];
    const float* b1 = (const float*)d_in[6];
    const float* m1 = (const float*)d_in[7];
    const float* v1 = (const float*)d_in[8];
    const float* g2 = (const float*)d_in[9];
    const float* b2 = (const float*)d_in[10];
    const float* m2 = (const float*)d_in[11];
    const float* v2 = (const float*)d_in[12];
    const float* g3 = (const float*)d_in[13];
    const float* b3 = (const float*)d_in[14];
    const float* m3 = (const float*)d_in[15];
    const float* v3 = (const float*)d_in[16];
    const float* tw = (const float*)d_in[17];
    const float* tb = (const float*)d_in[18];
    const float* tm = (const float*)d_in[19];
    const float* tv = (const float*)d_in[20];

    char* ws = (char*)d_ws;
    char* actA = ws + OFF_ACTA;
    char* wa1  = ws + OFF_WA1;
    char* wa2  = ws + OFF_WA2;
    char* wa3  = ws + OFF_WA3;
    char* wa4  = ws + OFF_WA4;
    int*  TH   = (int*)(ws + OFF_TH);

    prep_kernel<<<610, 256, 0, stream>>>(x, W1, W2, W3, W4,
                                         g1, b1, m1, v1, g2, b2, m2, v2,
                                         g3, b3, m3, v3,
                                         actA, wa1, wa2, wa3, wa4, TH);

    net_kernel<<<256, 1024, 0, stream>>>((const v4i*)actA,
                                         (const v4i*)wa1, (const v4i*)wa2,
                                         (const v4i*)wa3, (const v4i*)wa4,
                                         TH, tw, tb, tm, tv, (float*)d_out);
}